// Round 1
// baseline (364.656 us; speedup 1.0000x reference)
//
#include <hip/hip_runtime.h>
#include <math.h>

// Problem constants (from reference setup_inputs)
constexpr int B_ = 2048, C_ = 3, T_ = 300, J_ = 25;
constexpr int SLAB  = T_ * J_;          // 7500 floats per (b,c) slab, contiguous
constexpr int NBC   = B_ * C_;          // 6144 slabs
constexpr int NQ    = SLAB / 4;         // 1875 float4s per slab (exact)
constexpr int NCHUNK = (NQ + 63) / 64;  // 30 wave-chunks of 64 float4

// Async global->LDS, 16B per lane. LDS dest is wave-uniform base + lane*16.
__device__ __forceinline__ void gl_lds16(const float* g, float* l) {
  __builtin_amdgcn_global_load_lds(
      (const __attribute__((address_space(1))) void*)g,
      (__attribute__((address_space(3))) void*)l, 16, 0, 0);
}

__global__ __launch_bounds__(256) void slab_kernel(
    const float* __restrict__ gin, const float* __restrict__ gtg,
    float* __restrict__ rec_part, float* __restrict__ sm_part) {
  // 60 KB staging -> 2 blocks/CU (LDS-limited), 8 waves/CU
  __shared__ __align__(16) float s_in[SLAB];
  __shared__ __align__(16) float s_tg[SLAB];
  __shared__ float s_part[256];  // [strip 0..9][j 0..24]
  __shared__ float s_red[4];

  const int tid  = threadIdx.x;
  const int lane = tid & 63;
  const int wave = tid >> 6;
  const size_t base = (size_t)blockIdx.x * SLAB;
  const float* in = gin + base;
  const float* tg = gtg + base;

  // ---- Stage both slabs into LDS, coalesced 1KB-per-wave chunks ----
  for (int c = wave; c < NCHUNK; c += 4) {
    const int e = c * 64 + lane;          // float4 index; tail chunk exec-masked
    if (e < NQ) {
      gl_lds16(in + e * 4, s_in + c * 256);
      gl_lds16(tg + e * 4, s_tg + c * 256);
    }
  }
  __builtin_amdgcn_s_waitcnt(0);  // drain vmcnt before barrier
  __syncthreads();

  // ---- Reconstruction partial: sum (in - tg)^2 over the slab ----
  float racc = 0.f;
  const float4* v_in = (const float4*)s_in;
  const float4* v_tg = (const float4*)s_tg;
  for (int i = tid; i < NQ; i += 256) {
    float4 a = v_in[i], b = v_tg[i];
    float d0 = a.x - b.x, d1 = a.y - b.y, d2 = a.z - b.z, d3 = a.w - b.w;
    racc += d0 * d0 + d1 * d1 + d2 * d2 + d3 * d3;
  }

  // ---- Smooth partials: fixed j per thread (no dynamic reg indexing) ----
  // sx[j] = sum_{t=0..T-2} x[t,j]  -  sum_{t=1..T-1} x[t,j]^2  (reference quirk:
  // next frame squared, not squared difference). Contribution of element (t,j):
  // (t<T-1 ? x : 0) - (t>0 ? x^2 : 0).  Linear in elements -> strip-splittable.
  // We accumulate (x-term) - (y-term) per thread so abs happens only after the
  // full t-sum per j.
  if (tid < 250) {
    const int j  = tid % 25;
    const int s  = tid / 25;
    const int t0 = s * 30;  // 10 strips of 30 (T = 300 exactly)
    float p = 0.f;
    #pragma unroll
    for (int k = 0; k < 30; ++k) {
      const int t = t0 + k;
      const float x = s_in[t * 25 + j];
      const float y = s_tg[t * 25 + j];
      if (t < T_ - 1) p += x - y;                  // linear terms
      if (t > 0)      p += (y - x) * (y + x);      // y^2 - x^2
    }
    s_part[s * 25 + j] = p;
  }

  // ---- wave-reduce rec ----
  #pragma unroll
  for (int off = 32; off > 0; off >>= 1) racc += __shfl_down(racc, off, 64);
  if (lane == 0) s_red[wave] = racc;
  __syncthreads();

  // ---- wave 0: finish smooth (|.| over j<24) and write block partials ----
  if (wave == 0) {
    float aval = 0.f;
    if (lane < J_ - 1) {                 // reference excludes last joint
      float dx = 0.f;
      #pragma unroll
      for (int s = 0; s < 10; ++s) dx += s_part[s * 25 + lane];
      aval = fabsf(dx);
    }
    #pragma unroll
    for (int off = 32; off > 0; off >>= 1) aval += __shfl_down(aval, off, 64);
    if (lane == 0) {
      rec_part[blockIdx.x] = s_red[0] + s_red[1] + s_red[2] + s_red[3];
      sm_part[blockIdx.x]  = sqrtf(aval);
    }
  }
}

__global__ __launch_bounds__(256) void finalize_kernel(
    const float* __restrict__ rec_part, const float* __restrict__ sm_part,
    float* __restrict__ out) {
  const int tid  = threadIdx.x;
  const int lane = tid & 63;
  const int wave = tid >> 6;
  double r = 0.0, s = 0.0;
  for (int i = tid; i < NBC; i += 256) {
    r += (double)rec_part[i];
    s += (double)sm_part[i];
  }
  #pragma unroll
  for (int off = 32; off > 0; off >>= 1) {
    r += __shfl_down(r, off, 64);
    s += __shfl_down(s, off, 64);
  }
  __shared__ double sr[4], ss[4];
  if (lane == 0) { sr[wave] = r; ss[wave] = s; }
  __syncthreads();
  if (tid == 0) {
    const double rt = sr[0] + sr[1] + sr[2] + sr[3];
    const double st = ss[0] + ss[1] + ss[2] + ss[3];
    const double loss_rec    = rt / (double)((long long)B_ * C_ * T_ * J_);
    const double loss_smooth = (st / (double)NBC) / (double)(J_ * T_);
    out[0] = (float)(2.0 * loss_rec + 3.0 * loss_smooth);
  }
}

extern "C" void kernel_launch(void* const* d_in, const int* in_sizes, int n_in,
                              void* d_out, int out_size, void* d_ws, size_t ws_size,
                              hipStream_t stream) {
  const float* in = (const float*)d_in[0];
  const float* tg = (const float*)d_in[1];
  float* rec_part = (float*)d_ws;          // 6144 floats
  float* sm_part  = rec_part + NBC;        // 6144 floats (48 KB total)
  slab_kernel<<<NBC, 256, 0, stream>>>(in, tg, rec_part, sm_part);
  finalize_kernel<<<1, 256, 0, stream>>>(rec_part, sm_part, (float*)d_out);
}